// Round 1
// baseline (327.220 us; speedup 1.0000x reference)
//
#include <hip/hip_runtime.h>

typedef __bf16 bf16_t;
typedef __bf16 bf16x8 __attribute__((ext_vector_type(8)));
typedef float f32x4 __attribute__((ext_vector_type(4)));

#define CTOT 320
#define NPIX 32768  // 8*64*64

// ---------- P1: y [b][c][h][w] f32 -> yt [pix][320] bf16 (pixel-major) ----------
__global__ __launch_bounds__(256) void k_transpose_y(const float* __restrict__ y,
                                                     bf16_t* __restrict__ yt) {
  __shared__ bf16_t T[64][72];
  int blk = blockIdx.x;            // (8*64) * 5 blocks
  int c0 = (blk % 5) * 64;
  int bh = blk / 5;                // b*64 + h
  int b = bh >> 6, h = bh & 63;
  int tid = threadIdx.x;
  {
    int c = tid >> 2, w0 = (tid & 3) << 4;
    const float* src = y + (size_t)(b * CTOT + c0 + c) * 4096 + (h << 6) + w0;
#pragma unroll
    for (int j = 0; j < 16; j += 4) {
      float4 v = *(const float4*)(src + j);
      T[c][w0 + j + 0] = (bf16_t)v.x;
      T[c][w0 + j + 1] = (bf16_t)v.y;
      T[c][w0 + j + 2] = (bf16_t)v.z;
      T[c][w0 + j + 3] = (bf16_t)v.w;
    }
  }
  __syncthreads();
  {
    int w = tid >> 2, cq = (tid & 3) << 4;
    union { uint4 v; bf16_t b[8]; } u0, u1;
#pragma unroll
    for (int j = 0; j < 8; ++j) { u0.b[j] = T[cq + j][w]; u1.b[j] = T[cq + 8 + j][w]; }
    bf16_t* dst = yt + (size_t)((bh << 6) | w) * CTOT + c0 + cq;
    *(uint4*)dst = u0.v;
    *(uint4*)(dst + 8) = u1.v;
  }
}

// ---------- P2: w [oc][ic][5][5] f32 -> wt [tap][OCp][ICp] bf16 (zero-padded) ----------
__global__ __launch_bounds__(256) void k_transpose_w(const float* __restrict__ w,
                                                     bf16_t* __restrict__ wt,
                                                     int IC, int ICp, int OC, int OCp) {
  int idx = blockIdx.x * 256 + threadIdx.x;
  if (idx >= OCp * ICp) return;
  int oc = idx / ICp, ic = idx - oc * ICp;
  bool valid = (oc < OC) && (ic < IC);
  const float* src = w + (size_t)(oc * IC + ic) * 25;
#pragma unroll
  for (int t = 0; t < 25; ++t) {
    float v = valid ? src[t] : 0.0f;
    wt[(size_t)(t * OCp + oc) * ICp + ic] = (bf16_t)v;
  }
}

// ---------- main: implicit-GEMM conv, tap-major K, MFMA 16x16x32 bf16 ----------
struct ConvDesc {
  const float* bias;
  unsigned out_off;   // elements into d_out
  unsigned wt_off;    // elements into wt region
  int IC, ICp, OC, chs, masked, job_start, nmb;
};
struct MainParams {
  const bf16_t* yt;
  const bf16_t* wt;
  float* out;
  ConvDesc cv[9];
};

__global__ __launch_bounds__(256, 2) void k_conv_main(MainParams P) {
  // Sin: [icg 0..3][pixel lin 0..815 (12 rows x 68 cols)][8 ic]  = 52224 B
  // Sw : [buf][icg][oc 0..63][8 ic]                              =  8192 B
  __shared__ bf16_t Sin[4][816][8];
  __shared__ bf16_t Sw[2][4][64][8];

  int bid = blockIdx.x;
  int ci = 0;
#pragma unroll
  for (int i = 1; i < 9; ++i) if (bid >= P.cv[i].job_start) ci = i;
  ConvDesc cd = P.cv[ci];
  int local = bid - cd.job_start;
  int mb = local >> 6, nb = local & 63;      // 64 n-blocks (512 px each) per m-block
  int b = nb >> 3, r0 = (nb & 7) << 3;       // 8 output rows per n-block
  int tid = threadIdx.x, lane = tid & 63, wn = tid >> 6;
  int OCp = cd.nmb << 6;

  const bf16_t* sin0 = &Sin[0][0][0];
  const bf16_t* sw0 = &Sw[0][0][0][0];

  // per-nf fragment base offsets into Sin (elements); tap adds (dy*68+dx)*8
  int bbase[8];
#pragma unroll
  for (int nf = 0; nf < 8; ++nf) {
    int rl = (wn << 1) + (nf >> 2);                 // local output row 0..7
    int col = ((nf & 3) << 4) + (lane & 15);        // local col 0..63
    bbase[nf] = ((lane >> 4) * 6528) + (rl * 68 + col) * 8;
  }
  int abase = ((lane >> 4) << 9) + ((lane & 15) << 3);

  int mfmax = (cd.OC - (mb << 6)) >> 4; if (mfmax > 4) mfmax = 4;

  f32x4 acc[4][8];
#pragma unroll
  for (int i = 0; i < 4; ++i)
#pragma unroll
    for (int j = 0; j < 8; ++j) acc[i][j] = (f32x4){0.f, 0.f, 0.f, 0.f};

  const bf16_t* wtc = P.wt + cd.wt_off;
  int nchunks = cd.ICp >> 5;
  int s_oc = tid >> 2, s_icg = tid & 3;

  for (int cb = 0; cb < nchunks; ++cb) {
    int ic0 = cb << 5;
    // ---- stage input chunk: 12 rows x 68 cols x 32 ic, halo zero-filled ----
    for (int task = tid; task < 3264; task += 256) {
      int pidx = task >> 2, icg = task & 3;
      int rr = pidx / 68, cc = pidx - rr * 68;
      int h = r0 + rr - 2, w = cc - 2;
      int icc = ic0 + (icg << 3);
      uint4 v = {0u, 0u, 0u, 0u};
      bool ld = ((unsigned)h < 64u) && ((unsigned)w < 64u) && (icc < cd.IC);
      if (cd.masked && ((h + w) & 1)) ld = false;   // input * m0 (keep even parity)
      if (ld)
        v = *(const uint4*)(P.yt + (size_t)((((b << 6) + h) << 6) | w) * CTOT + cd.chs + icc);
      *(uint4*)(&Sin[icg][pidx][0]) = v;
    }
    // ---- stage weights tap 0 -> buf 0 ----
    {
      size_t wo = (size_t)((mb << 6) + s_oc) * cd.ICp + ic0 + (s_icg << 3);
      uint4 wv = *(const uint4*)(wtc + wo);
      *(uint4*)(&Sw[0][s_icg][s_oc][0]) = wv;
    }
    __syncthreads();

    for (int tap = 0; tap < 25; ++tap) {
      int cur = tap & 1;
      uint4 wv;
      if (tap < 24) {  // issue next-tap weight load early (write after MFMAs)
        size_t wo = (size_t)((tap + 1) * OCp + (mb << 6) + s_oc) * cd.ICp + ic0 + (s_icg << 3);
        wv = *(const uint4*)(wtc + wo);
      }
      int dy = tap / 5;
      int dx = tap - dy * 5;
      int toff = (dy * 68 + dx) << 3;

      bf16x8 af[4];
      const bf16_t* swc = sw0 + (cur << 11) + abase;
#pragma unroll
      for (int mf = 0; mf < 4; ++mf) af[mf] = *(const bf16x8*)(swc + (mf << 7));

#pragma unroll
      for (int nf = 0; nf < 8; ++nf) {
        bf16x8 bfrag = *(const bf16x8*)(sin0 + bbase[nf] + toff);
#pragma unroll
        for (int mf = 0; mf < 4; ++mf) {
          if (mf < mfmax)
            acc[mf][nf] = __builtin_amdgcn_mfma_f32_16x16x32_bf16(af[mf], bfrag, acc[mf][nf], 0, 0, 0);
        }
      }
      if (tap < 24) *(uint4*)(&Sw[cur ^ 1][s_icg][s_oc][0]) = wv;
      __syncthreads();
    }
  }

  // ---- epilogue: bias, output mask (1-m0), store f32 ----
  float* outp = P.out + cd.out_off;
  int laneq = lane >> 4;
#pragma unroll
  for (int mf = 0; mf < 4; ++mf) {
    if (mf >= mfmax) break;
    int oc0 = (mb << 6) + (mf << 4) + (laneq << 2);
    float b0 = cd.bias[oc0], b1 = cd.bias[oc0 + 1], b2 = cd.bias[oc0 + 2], b3 = cd.bias[oc0 + 3];
    size_t obase = (size_t)(b * cd.OC + oc0) << 12;
#pragma unroll
    for (int nf = 0; nf < 8; ++nf) {
      int nl = (wn << 7) + (nf << 4) + (lane & 15);
      int rem = (r0 << 6) + nl;
      int h = rem >> 6, w = rem & 63;
      float keep = 1.0f;
      if (cd.masked && !((h + w) & 1)) keep = 0.0f;  // * (1 - m0): keep odd parity
      f32x4 a = acc[mf][nf];
      outp[obase + rem]           = (a[0] + b0) * keep;
      outp[obase + 4096 + rem]    = (a[1] + b1) * keep;
      outp[obase + 8192 + rem]    = (a[2] + b2) * keep;
      outp[obase + 12288 + rem]   = (a[3] + b3) * keep;
    }
  }
}

extern "C" void kernel_launch(void* const* d_in, const int* in_sizes, int n_in,
                              void* d_out, int out_size, void* d_ws, size_t ws_size,
                              hipStream_t stream) {
  const float* y = (const float*)d_in[0];
  bf16_t* yt = (bf16_t*)d_ws;
  bf16_t* wt = (bf16_t*)((char*)d_ws + (size_t)NPIX * CTOT * 2);  // +20,971,520 B

  k_transpose_y<<<2560, 256, 0, stream>>>(y, yt);

  static const int IC[9]   = {16, 16, 32, 64, 192, 16, 32, 64, 128};
  static const int ICp[9]  = {32, 32, 32, 64, 192, 32, 32, 64, 128};
  static const int OC[9]   = {32, 32, 64, 128, 384, 32, 64, 128, 384};
  static const int OCpA[9] = {64, 64, 64, 128, 384, 64, 64, 128, 384};
  static const int WIDX[9] = {3, 5, 7, 9, 11, 13, 15, 17, 19};
  static const int BIDX[9] = {4, 6, 8, 10, 12, 14, 16, 18, 20};
  static const int CHS[9]  = {0, 16, 32, 64, 128, 0, 0, 0, 0};
  static const unsigned WTOFF[9]  = {0, 51200, 102400, 153600, 358400,
                                     2201600, 2252800, 2304000, 2508800};
  static const unsigned OUTOFF[9] = {0, 1048576, 3145728, 7340032, 15728640,
                                     2097152, 5242880, 11534336, 28311552};
  static const int JOBST[9]  = {0, 64, 128, 192, 320, 704, 768, 832, 960};
  static const int MASKED[9] = {1, 1, 1, 1, 1, 0, 0, 0, 0};

  for (int i = 0; i < 9; ++i) {
    int n = OCpA[i] * ICp[i];
    k_transpose_w<<<(n + 255) / 256, 256, 0, stream>>>(
        (const float*)d_in[WIDX[i]], wt + WTOFF[i], IC[i], ICp[i], OC[i], OCpA[i]);
  }

  MainParams P;
  P.yt = yt; P.wt = wt; P.out = (float*)d_out;
  for (int i = 0; i < 9; ++i) {
    P.cv[i].bias = (const float*)d_in[BIDX[i]];
    P.cv[i].out_off = OUTOFF[i];
    P.cv[i].wt_off = WTOFF[i];
    P.cv[i].IC = IC[i]; P.cv[i].ICp = ICp[i]; P.cv[i].OC = OC[i];
    P.cv[i].chs = CHS[i]; P.cv[i].masked = MASKED[i];
    P.cv[i].job_start = JOBST[i]; P.cv[i].nmb = OCpA[i] >> 6;
  }
  k_conv_main<<<1344, 256, 0, stream>>>(P);
}